// Round 17
// baseline (284.499 us; speedup 1.0000x reference)
//
#include <hip/hip_runtime.h>

typedef int i32x4 __attribute__((ext_vector_type(4)));

#define AS1 __attribute__((address_space(1)))
#define AS3 __attribute__((address_space(3)))

#define M_DIM 8192
#define N_DIM 8192
#define K_DIM 2048
#define NT 32   // K-tiles of 64 bytes

// ---------------- fused quantize: x (per-tensor), w (per-row), prep (scale+bias) -------
__global__ __launch_bounds__(256) void quant_all_kernel(
    const float* __restrict__ x, const float* __restrict__ w,
    const float* __restrict__ bias,
    const float* __restrict__ in_scale, const float* __restrict__ w_scale,
    const float* __restrict__ b_scale,
    i32x4* __restrict__ qx, i32x4* __restrict__ qw,
    float* __restrict__ oscale, float* __restrict__ obias)
{
    const int bid = blockIdx.x;
    if (bid < 8192) {
        const int idx = (bid & 4095) * 256 + threadIdx.x;   // 0..1048575
        const bool isx = bid < 4096;
        float s = isx ? in_scale[0] : w_scale[idx >> 7];
        const float4* p = reinterpret_cast<const float4*>(isx ? x : w) + (size_t)idx * 4;
        union { char c[16]; i32x4 v; } u;
#pragma unroll
        for (int v4 = 0; v4 < 4; ++v4) {
            float4 f = p[v4];
            u.c[v4*4+0] = (char)(int)fminf(fmaxf(rintf(f.x / s), -128.f), 127.f);
            u.c[v4*4+1] = (char)(int)fminf(fmaxf(rintf(f.y / s), -128.f), 127.f);
            u.c[v4*4+2] = (char)(int)fminf(fmaxf(rintf(f.z / s), -128.f), 127.f);
            u.c[v4*4+3] = (char)(int)fminf(fmaxf(rintf(f.w / s), -128.f), 127.f);
        }
        (isx ? qx : qw)[idx] = u.v;
    } else {
        const int i = (bid - 8192) * 256 + threadIdx.x;
        if (i < N_DIM) {
            oscale[i] = in_scale[0] * w_scale[i] * 0.5f;   // W_ALPHA
            float bs = b_scale[i];
            float q = fminf(fmaxf(rintf(bias[i] / bs), -128.f), 127.f);
            obias[i] = q * bs * 0.75f;                      // B_BETA
        }
    }
}

// ---------------- int8 GEMM: 128x128, wave-private LDS staging, ZERO barriers ----------
// R16 post-mortem: LDS service (513cy) and MFMA (327cy) fully serialized by the
// per-tile barrier+vmcnt convoy (measured 825cy/tile-step = 513+327). Fix: each
// wave stages ITS OWN A-rows and B-rows into a PRIVATE 8KB LDS region (sole
// reader) -> no cross-wave visibility needed -> NO s_barrier anywhere. Per-wave
// sync only: lgkmcnt(0) (own reads serviced) before in-place restage; vmcnt(0)
// (own 8 stage calls landed; covered by the ~327cy MFMA phase > L2 latency)
// before next tile's reads. Single buffer per wave -> LDS 32 KiB/block ->
// 4 blocks/CU, 16 fully independent wave-streams per CU (m114 maximized).
// Cost: A/B staged 2x (by both waves sharing the panel) -> LDS 64KB/block-tile,
// floor ~640cy/step, vs 825 measured today with the convoy on top.
// Swizzle: same verified family (read: slot kg ^ ((lrow>>1)&3); source
// pre-swizzled (t&3)^((t>>3)&3); linear lds dest) -> 0 conflicts (R2/R15/R16).
// L2: column-stripe XCD swizzle (R12/R15: FETCH ~100MB).
__global__ __launch_bounds__(256, 4) void gemm_i8_kernel(
    const char* __restrict__ qx,   // [M][K] int8
    const char* __restrict__ qw,   // [N][K] int8
    const float* __restrict__ oscale,
    const float* __restrict__ obias,
    float* __restrict__ out)       // [M][N] fp32
{
    __shared__ __align__(16) char lds[4 * 8192];   // per wave: A 4KB + B 4KB

    const int t    = threadIdx.x;          // 0..255
    const int lane = t & 63;
    const int wid  = t >> 6;               // 0..3
    const int wm   = wid >> 1;             // 0..1
    const int wn   = wid & 1;              // 0..1

    // XCD column-stripe swizzle (R12/R15-proven locality)
    int bid = blockIdx.x;                   // 4096 blocks
    int sl  = bid >> 3;                     // 0..511
    const size_t brow = (size_t)(sl >> 3) * 128;                    // 64 row-blocks
    const size_t bcol = (size_t)((bid & 7) * 8 + (sl & 7)) * 128;   // 64 col-blocks

    // per-wave private staging: call c covers rows c*16 + lane/4, phys slot lane&3
    // (linear dest). Global source pre-swizzled: logical slot =
    // (lane&3) ^ ((row>>1)&3) = (lane&3) ^ ((lane>>3)&3)  [c*16 invariant mod 4].
    const int srow  = lane >> 2;           // 0..15
    const int lslot = (lane & 3) ^ ((lane >> 3) & 3);
    const char* srcA = qx + (brow + (size_t)wm * 64 + srow) * K_DIM + lslot * 16;
    const char* srcB = qw + (bcol + (size_t)wn * 64 + srow) * K_DIM + lslot * 16;
    char* ldsWA = lds + wid * 8192 + lane * 16;          // wave-private A
    char* ldsWB = lds + wid * 8192 + 4096 + lane * 16;   // wave-private B

    // 8 calls: 4 x A (16 rows each), 4 x B
#define STAGEW(ko_) do {                                                                  \
    __builtin_amdgcn_global_load_lds((const AS1 unsigned int*)(srcA + (ko_)),             \
        (AS3 unsigned int*)(ldsWA), 16, 0, 0);                                            \
    __builtin_amdgcn_global_load_lds((const AS1 unsigned int*)(srcA + (ko_) + 16 * K_DIM),\
        (AS3 unsigned int*)(ldsWA + 1024), 16, 0, 0);                                     \
    __builtin_amdgcn_global_load_lds((const AS1 unsigned int*)(srcA + (ko_) + 32 * K_DIM),\
        (AS3 unsigned int*)(ldsWA + 2048), 16, 0, 0);                                     \
    __builtin_amdgcn_global_load_lds((const AS1 unsigned int*)(srcA + (ko_) + 48 * K_DIM),\
        (AS3 unsigned int*)(ldsWA + 3072), 16, 0, 0);                                     \
    __builtin_amdgcn_global_load_lds((const AS1 unsigned int*)(srcB + (ko_)),             \
        (AS3 unsigned int*)(ldsWB), 16, 0, 0);                                            \
    __builtin_amdgcn_global_load_lds((const AS1 unsigned int*)(srcB + (ko_) + 16 * K_DIM),\
        (AS3 unsigned int*)(ldsWB + 1024), 16, 0, 0);                                     \
    __builtin_amdgcn_global_load_lds((const AS1 unsigned int*)(srcB + (ko_) + 32 * K_DIM),\
        (AS3 unsigned int*)(ldsWB + 2048), 16, 0, 0);                                     \
    __builtin_amdgcn_global_load_lds((const AS1 unsigned int*)(srcB + (ko_) + 48 * K_DIM),\
        (AS3 unsigned int*)(ldsWB + 3072), 16, 0, 0);                                     \
  } while (0)

    // read offsets within the wave-private region (swizzled; frag step = 1024 B):
    // row lrow (+16 per frag), slot kg ^ ((lrow>>1)&3).
    const int lrow = lane & 15;
    const int kg   = lane >> 4;            // 16B k-group 0..3
    const int swz  = (kg ^ ((lrow >> 1) & 3)) << 4;
    const char* rdA = lds + wid * 8192 + lrow * 64 + swz;
    const char* rdB = lds + wid * 8192 + 4096 + lrow * 64 + swz;

    i32x4 acc[4][4];
#pragma unroll
    for (int m = 0; m < 4; ++m)
#pragma unroll
        for (int n = 0; n < 4; ++n)
            acc[m][n] = (i32x4){0, 0, 0, 0};

#define MM(m_, n_, a_, b_) acc[m_][n_] = __builtin_amdgcn_mfma_i32_16x16x64_i8((a_), (b_), acc[m_][n_], 0, 0, 0)
#define LGKM0() do { asm volatile("s_waitcnt lgkmcnt(0)" ::: "memory"); __builtin_amdgcn_sched_barrier(0); } while (0)
#define VMCNT0() do { asm volatile("s_waitcnt vmcnt(0)" ::: "memory"); __builtin_amdgcn_sched_barrier(0); } while (0)

    // prologue: stage tile 0 into the private buffer; wait for it (own loads only)
    STAGEW(0);
    VMCNT0();

    for (int tt = 0; tt < NT; ++tt) {
        // reads from the private buffer (certified by VMCNT0 of prev iter)
        i32x4 a0 = *(const i32x4*)(rdA);
        i32x4 a1 = *(const i32x4*)(rdA + 1024);
        i32x4 a2 = *(const i32x4*)(rdA + 2048);
        i32x4 a3 = *(const i32x4*)(rdA + 3072);
        i32x4 b0 = *(const i32x4*)(rdB);
        i32x4 b1 = *(const i32x4*)(rdB + 1024);
        i32x4 b2 = *(const i32x4*)(rdB + 2048);
        i32x4 b3 = *(const i32x4*)(rdB + 3072);

        LGKM0();   // own ds_reads serviced -> safe to overwrite in place

        if (tt + 1 < NT) STAGEW((tt + 1) * 64);   // restage same buffer, next K-slab

        MM(0,0,a0,b0); MM(0,1,a0,b1); MM(0,2,a0,b2); MM(0,3,a0,b3);
        MM(1,0,a1,b0); MM(1,1,a1,b1); MM(1,2,a1,b2); MM(1,3,a1,b3);
        MM(2,0,a2,b0); MM(2,1,a2,b1); MM(2,2,a2,b2); MM(2,3,a2,b3);
        MM(3,0,a3,b0); MM(3,1,a3,b1); MM(3,2,a3,b2); MM(3,3,a3,b3);

        if (tt + 1 < NT) VMCNT0();   // own 8 stage calls landed (covered by 16 MFMA)
    }
#undef STAGEW
#undef MM
#undef LGKM0
#undef VMCNT0

    // epilogue: C/D layout col = lane&15, row = (lane>>4)*4 + j
    const int colq = lane & 15;
    const int rowq = lane >> 4;
#pragma unroll
    for (int n = 0; n < 4; ++n) {
        size_t col = bcol + wn * 64 + n * 16 + colq;
        float sc = oscale[col];
        float bi = obias[col];
#pragma unroll
        for (int m = 0; m < 4; ++m) {
            size_t rbase = brow + wm * 64 + m * 16 + (size_t)rowq * 4;
#pragma unroll
            for (int j = 0; j < 4; ++j)
                out[(rbase + j) * N_DIM + col] = (float)acc[m][n][j] * sc + bi;
        }
    }
}

extern "C" void kernel_launch(void* const* d_in, const int* in_sizes, int n_in,
                              void* d_out, int out_size, void* d_ws, size_t ws_size,
                              hipStream_t stream) {
    const float* x        = (const float*)d_in[0];
    const float* weight   = (const float*)d_in[1];
    const float* bias     = (const float*)d_in[2];
    const float* in_scale = (const float*)d_in[3];
    const float* w_scale  = (const float*)d_in[4];
    const float* b_scale  = (const float*)d_in[5];
    float* out = (float*)d_out;

    char* ws = (char*)d_ws;
    const size_t xk = (size_t)M_DIM * K_DIM;
    const size_t wk = (size_t)N_DIM * K_DIM;
    char*  qx     = ws;
    char*  qw     = ws + xk;
    float* oscale = (float*)(ws + xk + wk);
    float* obias  = oscale + N_DIM;

    quant_all_kernel<<<8224, 256, 0, stream>>>(x, weight, bias, in_scale, w_scale,
                                               b_scale, (i32x4*)qx, (i32x4*)qw,
                                               oscale, obias);
    gemm_i8_kernel<<<4096, 256, 0, stream>>>(qx, qw, oscale, obias, out);
}

// Round 18
// 222.251 us; speedup vs baseline: 1.2801x; 1.2801x over previous
//
#include <hip/hip_runtime.h>

typedef int i32x4 __attribute__((ext_vector_type(4)));

#define AS1 __attribute__((address_space(1)))
#define AS3 __attribute__((address_space(3)))

#define M_DIM 8192
#define N_DIM 8192
#define K_DIM 2048
#define NT 32   // K-tiles of 64 bytes

// ---------------- fused quantize, 128B/thread: x (per-tensor), w (per-row), prep -------
// blocks [0,2048): x, [2048,4096): w — each thread quantizes 32 elems (2 i32x4 items);
// blocks [4096,4128): oscale/obias prep. Item pair (2i,2i+1) never straddles a row
// (row = item>>7 changes only at even->odd boundaries of 128; 2i+1 is odd) -> one
// w_scale fetch per thread.
__global__ __launch_bounds__(256) void quant_all_kernel(
    const float* __restrict__ x, const float* __restrict__ w,
    const float* __restrict__ bias,
    const float* __restrict__ in_scale, const float* __restrict__ w_scale,
    const float* __restrict__ b_scale,
    i32x4* __restrict__ qx, i32x4* __restrict__ qw,
    float* __restrict__ oscale, float* __restrict__ obias)
{
    const int bid = blockIdx.x;
    if (bid < 4096) {
        const bool isx = bid < 2048;
        const int tid = (bid & 2047) * 256 + threadIdx.x;   // 0..524287
        const int item0 = tid * 2;                          // first of 2 i32x4 items
        float s = isx ? in_scale[0] : w_scale[item0 >> 7];
        const float4* p = reinterpret_cast<const float4*>(isx ? x : w) + (size_t)item0 * 4;
        i32x4* qo = (isx ? qx : qw) + item0;
#pragma unroll
        for (int it = 0; it < 2; ++it) {
            union { char c[16]; i32x4 v; } u;
#pragma unroll
            for (int v4 = 0; v4 < 4; ++v4) {
                float4 f = p[it * 4 + v4];
                u.c[v4*4+0] = (char)(int)fminf(fmaxf(rintf(f.x / s), -128.f), 127.f);
                u.c[v4*4+1] = (char)(int)fminf(fmaxf(rintf(f.y / s), -128.f), 127.f);
                u.c[v4*4+2] = (char)(int)fminf(fmaxf(rintf(f.z / s), -128.f), 127.f);
                u.c[v4*4+3] = (char)(int)fminf(fmaxf(rintf(f.w / s), -128.f), 127.f);
            }
            qo[it] = u.v;
        }
    } else {
        const int i = (bid - 4096) * 256 + threadIdx.x;
        if (i < N_DIM) {
            oscale[i] = in_scale[0] * w_scale[i] * 0.5f;   // W_ALPHA
            float bs = b_scale[i];
            float q = fminf(fmaxf(rintf(bias[i] / bs), -128.f), 127.f);
            obias[i] = q * bs * 0.75f;                      // B_BETA
        }
    }
}

// ---------------- int8 GEMM: 128x128 tile, 4 waves of 64x64, 4 blocks/CU ----------------
// FROZEN R16 kernel (175-177us, best): 4-way block independence (m114), column-
// stripe XCD swizzle (FETCH ~120MB), R2-verified swizzle (0 conflicts), reads-
// before-stage, no setprio, 2-tile unroll. Measured at ~82% of its LDS-BW ceiling
// (48KB/block-tile through ~85-93 B/cy/CU); schedule variations are null here.
__global__ __launch_bounds__(256, 4) void gemm_i8_kernel(
    const char* __restrict__ qx,   // [M][K] int8
    const char* __restrict__ qw,   // [N][K] int8
    const float* __restrict__ oscale,
    const float* __restrict__ obias,
    float* __restrict__ out)       // [M][N] fp32
{
    __shared__ __align__(16) char ldsA[2 * 8192];
    __shared__ __align__(16) char ldsB[2 * 8192];

    const int t    = threadIdx.x;          // 0..255
    const int lane = t & 63;
    const int wid  = t >> 6;               // 0..3
    const int wm   = wid >> 1;             // 0..1
    const int wn   = wid & 1;              // 0..1

    // XCD column-stripe swizzle (R12/R15-proven locality)
    int bid = blockIdx.x;                   // 4096 blocks
    int sl  = bid >> 3;                     // 0..511
    const size_t brow = (size_t)(sl >> 3) * 128;                    // 64 row-blocks
    const size_t bcol = (size_t)((bid & 7) * 8 + (sl & 7)) * 128;   // 64 col-blocks

    // staging: thread t covers row c*64 + t/4, 16B slot t&3 (linear dest);
    // global source pre-swizzled: logical slot = (t&3) ^ ((t>>3)&3)  (rule 21).
    const int srow  = t >> 2;              // 0..63
    const int lslot = (t & 3) ^ ((t >> 3) & 3);
    const char* gA = qx + (brow + srow) * K_DIM + lslot * 16;
    const char* gB = qw + (bcol + srow) * K_DIM + lslot * 16;
    char* dstA = ldsA + t * 16;
    char* dstB = ldsB + t * 16;

#define STAGE(tt_, bb_) do {                                                              \
    const int ko_ = (tt_) * 64;                                                           \
    __builtin_amdgcn_global_load_lds((const AS1 unsigned int*)(gA + ko_),                 \
        (AS3 unsigned int*)(dstA + (bb_) * 8192), 16, 0, 0);                              \
    __builtin_amdgcn_global_load_lds((const AS1 unsigned int*)(gA + ko_ + 64 * K_DIM),    \
        (AS3 unsigned int*)(dstA + (bb_) * 8192 + 4096), 16, 0, 0);                       \
    __builtin_amdgcn_global_load_lds((const AS1 unsigned int*)(gB + ko_),                 \
        (AS3 unsigned int*)(dstB + (bb_) * 8192), 16, 0, 0);                              \
    __builtin_amdgcn_global_load_lds((const AS1 unsigned int*)(gB + ko_ + 64 * K_DIM),    \
        (AS3 unsigned int*)(dstB + (bb_) * 8192 + 4096), 16, 0, 0);                       \
  } while (0)

    // frag read offsets (swizzled): row r, slot kg ^ ((r>>1)&3); frag step = +1024 B.
    const int lrow = lane & 15;
    const int kg   = lane >> 4;            // 16B k-group 0..3
    const int rA   = wm * 64 + lrow;
    const int rB   = wn * 64 + lrow;
    const int offA0 = rA * 64 + ((kg ^ ((rA >> 1) & 3)) * 16);
    const int offB0 = rB * 64 + ((kg ^ ((rB >> 1) & 3)) * 16);

    i32x4 acc[4][4];
#pragma unroll
    for (int m = 0; m < 4; ++m)
#pragma unroll
        for (int n = 0; n < 4; ++n)
            acc[m][n] = (i32x4){0, 0, 0, 0};

#define MM(m_, n_, a_, b_) acc[m_][n_] = __builtin_amdgcn_mfma_i32_16x16x64_i8((a_), (b_), acc[m_][n_], 0, 0, 0)
#define BAR() do { __builtin_amdgcn_s_barrier(); asm volatile("" ::: "memory"); } while (0)
#define VMCNT0() asm volatile("s_waitcnt vmcnt(0)" ::: "memory")

#define KT(tt_, cb_, PF_) do {                                                            \
    const char* bA = ldsA + (cb_) * 8192;                                                 \
    const char* bB = ldsB + (cb_) * 8192;                                                 \
    i32x4 a0 = *(const i32x4*)(bA + offA0);                                               \
    i32x4 a1 = *(const i32x4*)(bA + offA0 + 1024);                                        \
    i32x4 a2 = *(const i32x4*)(bA + offA0 + 2048);                                        \
    i32x4 a3 = *(const i32x4*)(bA + offA0 + 3072);                                        \
    i32x4 b0 = *(const i32x4*)(bB + offB0);                                               \
    i32x4 b1 = *(const i32x4*)(bB + offB0 + 1024);                                        \
    i32x4 b2 = *(const i32x4*)(bB + offB0 + 2048);                                        \
    i32x4 b3 = *(const i32x4*)(bB + offB0 + 3072);                                        \
    if (PF_) STAGE((tt_) + 1, (cb_) ^ 1);                                                 \
    MM(0,0,a0,b0); MM(0,1,a0,b1); MM(0,2,a0,b2); MM(0,3,a0,b3);                           \
    MM(1,0,a1,b0); MM(1,1,a1,b1); MM(1,2,a1,b2); MM(1,3,a1,b3);                           \
    MM(2,0,a2,b0); MM(2,1,a2,b1); MM(2,2,a2,b2); MM(2,3,a2,b3);                           \
    MM(3,0,a3,b0); MM(3,1,a3,b1); MM(3,2,a3,b2); MM(3,3,a3,b3);                           \
    if (PF_) { VMCNT0(); BAR(); }                                                         \
  } while (0)

    // prologue: tile 0 staged and certified
    STAGE(0, 0);
    VMCNT0();
    BAR();

    for (int it = 0; it < 15; ++it) {      // tiles 0..29
        KT(2*it,     0, 1);
        KT(2*it + 1, 1, 1);
    }
    KT(30, 0, 1);   // stages tile 31
    KT(31, 1, 0);   // final tile, no prefetch/no trailing sync

#undef KT
#undef STAGE
#undef MM
#undef BAR
#undef VMCNT0

    // epilogue: C/D layout col = lane&15, row = (lane>>4)*4 + j
    const int colq = lane & 15;
    const int rowq = lane >> 4;
#pragma unroll
    for (int n = 0; n < 4; ++n) {
        size_t col = bcol + wn * 64 + n * 16 + colq;
        float sc = oscale[col];
        float bi = obias[col];
#pragma unroll
        for (int m = 0; m < 4; ++m) {
            size_t rbase = brow + wm * 64 + m * 16 + (size_t)rowq * 4;
#pragma unroll
            for (int j = 0; j < 4; ++j)
                out[(rbase + j) * N_DIM + col] = (float)acc[m][n][j] * sc + bi;
        }
    }
}

extern "C" void kernel_launch(void* const* d_in, const int* in_sizes, int n_in,
                              void* d_out, int out_size, void* d_ws, size_t ws_size,
                              hipStream_t stream) {
    const float* x        = (const float*)d_in[0];
    const float* weight   = (const float*)d_in[1];
    const float* bias     = (const float*)d_in[2];
    const float* in_scale = (const float*)d_in[3];
    const float* w_scale  = (const float*)d_in[4];
    const float* b_scale  = (const float*)d_in[5];
    float* out = (float*)d_out;

    char* ws = (char*)d_ws;
    const size_t xk = (size_t)M_DIM * K_DIM;
    const size_t wk = (size_t)N_DIM * K_DIM;
    char*  qx     = ws;
    char*  qw     = ws + xk;
    float* oscale = (float*)(ws + xk + wk);
    float* obias  = oscale + N_DIM;

    quant_all_kernel<<<4128, 256, 0, stream>>>(x, weight, bias, in_scale, w_scale,
                                               b_scale, (i32x4*)qx, (i32x4*)qw,
                                               oscale, obias);
    gemm_i8_kernel<<<4096, 256, 0, stream>>>(qx, qw, oscale, obias, out);
}

// Round 19
// 201.116 us; speedup vs baseline: 1.4146x; 1.1051x over previous
//
#include <hip/hip_runtime.h>

typedef int i32x4 __attribute__((ext_vector_type(4)));

#define AS1 __attribute__((address_space(1)))
#define AS3 __attribute__((address_space(3)))

#define M_DIM 8192
#define N_DIM 8192
#define K_DIM 2048
#define NT 32   // K-tiles of 64 bytes

// ---------------- fused quantize (R16 version — best measured): x, w, prep ----------
__global__ __launch_bounds__(256) void quant_all_kernel(
    const float* __restrict__ x, const float* __restrict__ w,
    const float* __restrict__ bias,
    const float* __restrict__ in_scale, const float* __restrict__ w_scale,
    const float* __restrict__ b_scale,
    i32x4* __restrict__ qx, i32x4* __restrict__ qw,
    float* __restrict__ oscale, float* __restrict__ obias)
{
    const int bid = blockIdx.x;
    if (bid < 8192) {
        const int idx = (bid & 4095) * 256 + threadIdx.x;   // 0..1048575
        const bool isx = bid < 4096;
        float s = isx ? in_scale[0] : w_scale[idx >> 7];
        const float4* p = reinterpret_cast<const float4*>(isx ? x : w) + (size_t)idx * 4;
        union { char c[16]; i32x4 v; } u;
#pragma unroll
        for (int v4 = 0; v4 < 4; ++v4) {
            float4 f = p[v4];
            u.c[v4*4+0] = (char)(int)fminf(fmaxf(rintf(f.x / s), -128.f), 127.f);
            u.c[v4*4+1] = (char)(int)fminf(fmaxf(rintf(f.y / s), -128.f), 127.f);
            u.c[v4*4+2] = (char)(int)fminf(fmaxf(rintf(f.z / s), -128.f), 127.f);
            u.c[v4*4+3] = (char)(int)fminf(fmaxf(rintf(f.w / s), -128.f), 127.f);
        }
        (isx ? qx : qw)[idx] = u.v;
    } else {
        const int i = (bid - 8192) * 256 + threadIdx.x;
        if (i < N_DIM) {
            oscale[i] = in_scale[0] * w_scale[i] * 0.5f;   // W_ALPHA
            float bs = b_scale[i];
            float q = fminf(fmaxf(rintf(bias[i] / bs), -128.f), 127.f);
            obias[i] = q * bs * 0.75f;                      // B_BETA
        }
    }
}

// ---------------- int8 GEMM: 128x128 tile, 4 waves of 64x64, 4 blocks/CU ----------------
// FROZEN R16 structure (175-177us best): 4-way block independence (m114), column-
// stripe XCD swizzle, R2-verified swizzle (0 conflicts), reads-before-stage, no
// setprio, 2-tile unroll. Only change vs R16: NONTEMPORAL C-stores (C is
// write-once/never-read; bypassing L2 preserves A/B panel residency for the
// co-resident blocks still in their K-loops).
__global__ __launch_bounds__(256, 4) void gemm_i8_kernel(
    const char* __restrict__ qx,   // [M][K] int8
    const char* __restrict__ qw,   // [N][K] int8
    const float* __restrict__ oscale,
    const float* __restrict__ obias,
    float* __restrict__ out)       // [M][N] fp32
{
    __shared__ __align__(16) char ldsA[2 * 8192];
    __shared__ __align__(16) char ldsB[2 * 8192];

    const int t    = threadIdx.x;          // 0..255
    const int lane = t & 63;
    const int wid  = t >> 6;               // 0..3
    const int wm   = wid >> 1;             // 0..1
    const int wn   = wid & 1;              // 0..1

    // XCD column-stripe swizzle (R12/R15-proven locality)
    int bid = blockIdx.x;                   // 4096 blocks
    int sl  = bid >> 3;                     // 0..511
    const size_t brow = (size_t)(sl >> 3) * 128;                    // 64 row-blocks
    const size_t bcol = (size_t)((bid & 7) * 8 + (sl & 7)) * 128;   // 64 col-blocks

    // staging: thread t covers row c*64 + t/4, 16B slot t&3 (linear dest);
    // global source pre-swizzled: logical slot = (t&3) ^ ((t>>3)&3)  (rule 21).
    const int srow  = t >> 2;              // 0..63
    const int lslot = (t & 3) ^ ((t >> 3) & 3);
    const char* gA = qx + (brow + srow) * K_DIM + lslot * 16;
    const char* gB = qw + (bcol + srow) * K_DIM + lslot * 16;
    char* dstA = ldsA + t * 16;
    char* dstB = ldsB + t * 16;

#define STAGE(tt_, bb_) do {                                                              \
    const int ko_ = (tt_) * 64;                                                           \
    __builtin_amdgcn_global_load_lds((const AS1 unsigned int*)(gA + ko_),                 \
        (AS3 unsigned int*)(dstA + (bb_) * 8192), 16, 0, 0);                              \
    __builtin_amdgcn_global_load_lds((const AS1 unsigned int*)(gA + ko_ + 64 * K_DIM),    \
        (AS3 unsigned int*)(dstA + (bb_) * 8192 + 4096), 16, 0, 0);                       \
    __builtin_amdgcn_global_load_lds((const AS1 unsigned int*)(gB + ko_),                 \
        (AS3 unsigned int*)(dstB + (bb_) * 8192), 16, 0, 0);                              \
    __builtin_amdgcn_global_load_lds((const AS1 unsigned int*)(gB + ko_ + 64 * K_DIM),    \
        (AS3 unsigned int*)(dstB + (bb_) * 8192 + 4096), 16, 0, 0);                       \
  } while (0)

    // frag read offsets (swizzled): row r, slot kg ^ ((r>>1)&3); frag step = +1024 B.
    const int lrow = lane & 15;
    const int kg   = lane >> 4;            // 16B k-group 0..3
    const int rA   = wm * 64 + lrow;
    const int rB   = wn * 64 + lrow;
    const int offA0 = rA * 64 + ((kg ^ ((rA >> 1) & 3)) * 16);
    const int offB0 = rB * 64 + ((kg ^ ((rB >> 1) & 3)) * 16);

    i32x4 acc[4][4];
#pragma unroll
    for (int m = 0; m < 4; ++m)
#pragma unroll
        for (int n = 0; n < 4; ++n)
            acc[m][n] = (i32x4){0, 0, 0, 0};

#define MM(m_, n_, a_, b_) acc[m_][n_] = __builtin_amdgcn_mfma_i32_16x16x64_i8((a_), (b_), acc[m_][n_], 0, 0, 0)
#define BAR() do { __builtin_amdgcn_s_barrier(); asm volatile("" ::: "memory"); } while (0)
#define VMCNT0() asm volatile("s_waitcnt vmcnt(0)" ::: "memory")

#define KT(tt_, cb_, PF_) do {                                                            \
    const char* bA = ldsA + (cb_) * 8192;                                                 \
    const char* bB = ldsB + (cb_) * 8192;                                                 \
    i32x4 a0 = *(const i32x4*)(bA + offA0);                                               \
    i32x4 a1 = *(const i32x4*)(bA + offA0 + 1024);                                        \
    i32x4 a2 = *(const i32x4*)(bA + offA0 + 2048);                                        \
    i32x4 a3 = *(const i32x4*)(bA + offA0 + 3072);                                        \
    i32x4 b0 = *(const i32x4*)(bB + offB0);                                               \
    i32x4 b1 = *(const i32x4*)(bB + offB0 + 1024);                                        \
    i32x4 b2 = *(const i32x4*)(bB + offB0 + 2048);                                        \
    i32x4 b3 = *(const i32x4*)(bB + offB0 + 3072);                                        \
    if (PF_) STAGE((tt_) + 1, (cb_) ^ 1);                                                 \
    MM(0,0,a0,b0); MM(0,1,a0,b1); MM(0,2,a0,b2); MM(0,3,a0,b3);                           \
    MM(1,0,a1,b0); MM(1,1,a1,b1); MM(1,2,a1,b2); MM(1,3,a1,b3);                           \
    MM(2,0,a2,b0); MM(2,1,a2,b1); MM(2,2,a2,b2); MM(2,3,a2,b3);                           \
    MM(3,0,a3,b0); MM(3,1,a3,b1); MM(3,2,a3,b2); MM(3,3,a3,b3);                           \
    if (PF_) { VMCNT0(); BAR(); }                                                         \
  } while (0)

    // prologue: tile 0 staged and certified
    STAGE(0, 0);
    VMCNT0();
    BAR();

    for (int it = 0; it < 15; ++it) {      // tiles 0..29
        KT(2*it,     0, 1);
        KT(2*it + 1, 1, 1);
    }
    KT(30, 0, 1);   // stages tile 31
    KT(31, 1, 0);   // final tile, no prefetch/no trailing sync

#undef KT
#undef STAGE
#undef MM
#undef BAR
#undef VMCNT0

    // epilogue: C/D layout col = lane&15, row = (lane>>4)*4 + j. Nontemporal
    // stores: C is write-once; keep it out of L2 so A/B panels stay resident.
    const int colq = lane & 15;
    const int rowq = lane >> 4;
#pragma unroll
    for (int n = 0; n < 4; ++n) {
        size_t col = bcol + wn * 64 + n * 16 + colq;
        float sc = oscale[col];
        float bi = obias[col];
#pragma unroll
        for (int m = 0; m < 4; ++m) {
            size_t rbase = brow + wm * 64 + m * 16 + (size_t)rowq * 4;
#pragma unroll
            for (int j = 0; j < 4; ++j)
                __builtin_nontemporal_store((float)acc[m][n][j] * sc + bi,
                                            &out[(rbase + j) * N_DIM + col]);
        }
    }
}

extern "C" void kernel_launch(void* const* d_in, const int* in_sizes, int n_in,
                              void* d_out, int out_size, void* d_ws, size_t ws_size,
                              hipStream_t stream) {
    const float* x        = (const float*)d_in[0];
    const float* weight   = (const float*)d_in[1];
    const float* bias     = (const float*)d_in[2];
    const float* in_scale = (const float*)d_in[3];
    const float* w_scale  = (const float*)d_in[4];
    const float* b_scale  = (const float*)d_in[5];
    float* out = (float*)d_out;

    char* ws = (char*)d_ws;
    const size_t xk = (size_t)M_DIM * K_DIM;
    const size_t wk = (size_t)N_DIM * K_DIM;
    char*  qx     = ws;
    char*  qw     = ws + xk;
    float* oscale = (float*)(ws + xk + wk);
    float* obias  = oscale + N_DIM;

    quant_all_kernel<<<8224, 256, 0, stream>>>(x, weight, bias, in_scale, w_scale,
                                               b_scale, (i32x4*)qx, (i32x4*)qw,
                                               oscale, obias);
    gemm_i8_kernel<<<4096, 256, 0, stream>>>(qx, qw, oscale, obias, out);
}